// Round 13
// baseline (1476.393 us; speedup 1.0000x reference)
//
#include <hip/hip_runtime.h>
#include <hip/hip_bf16.h>

// DimeNet++ forward: front/tail/outchain on MFMA (split-bf16, operand-swapped).
// This round: tail/front wave-tile split 2m x 4n (halves LDS ds_read traffic);
// k_agg reverted to 4-deep sequential unroll (r11 version).
namespace {
constexpr int E     = 120000;
constexpr int T     = 800000;
constexpr int NN    = 12000;
constexpr int H     = 128;
constexpr int INTD  = 64;
constexpr int BE    = 8;
constexpr int R     = 6;
constexpr int SR    = 42;
constexpr int OE    = 256;
constexpr float CUTOFF = 5.0f;
// packed interaction weights per block:
// [Wji 16384 | Wkj 16384 | Wdown 8192 | Wup 8192 | W0 W1 Wlin W2 W3 W4 W5 7x16384]
constexpr int PKB   = 163840;
constexpr int TAILO = 40960;
// packed output-block weights: [Wup 32768 | Wlin0,1,2 3x65536]
constexpr int OPKB  = 229376;
}

typedef __attribute__((ext_vector_type(8))) short bf16x8;
typedef __attribute__((ext_vector_type(4))) float f32x4;

__device__ __forceinline__ float silu_f(float x) { return x / (1.0f + __expf(-x)); }

__device__ __forceinline__ unsigned fbits(float x) {
    union { float f; unsigned u; } v; v.f = x; return v.u;
}
__device__ __forceinline__ float fof(unsigned u) {
    union { float f; unsigned u; } v; v.u = u; return v.f;
}
__device__ __forceinline__ unsigned short bf16_rn(float x) {
    unsigned u = fbits(x);
    unsigned r = u + 0x7FFFu + ((u >> 16) & 1u);
    return (unsigned short)(r >> 16);
}
__device__ __forceinline__ float bf16_f(unsigned short h) { return fof(((unsigned)h) << 16); }

// truncation split: x = hi + lo; packs two elements' hi into h, lo into l.
__device__ __forceinline__ void pack2(float x0, float x1, unsigned& h, unsigned& l) {
    const unsigned u0 = fbits(x0), u1 = fbits(x1);
    const unsigned t0 = u0 & 0xFFFF0000u, t1 = u1 & 0xFFFF0000u;
    h = (u0 >> 16) | t1;
    l = (fbits(x0 - fof(t0)) >> 16) | (fbits(x1 - fof(t1)) & 0xFFFF0000u);
}

// ---------------------------------------------------------------------------
// rbf[E,6]
// ---------------------------------------------------------------------------
__global__ void k_rbf(const float* __restrict__ dist, const float* __restrict__ freq,
                      float* __restrict__ rbf) {
    int e = blockIdx.x * blockDim.x + threadIdx.x;
    if (e >= E) return;
    float d  = dist[e] * (1.0f / CUTOFF);
    float d2 = d * d;
    float d5 = d2 * d2 * d;
    float env = 1.0f / d - 28.0f * d5 + 48.0f * d5 * d - 21.0f * d5 * d2;
    #pragma unroll
    for (int i = 0; i < R; ++i) rbf[e * R + i] = env * sinf(freq[i] * d);
}

// ---------------------------------------------------------------------------
// CSR build
// ---------------------------------------------------------------------------
__global__ void k_count(const int* __restrict__ idx, int n, int* __restrict__ cnt) {
    int i = blockIdx.x * 256 + threadIdx.x;
    if (i < n) atomicAdd(&cnt[idx[i]], 1);
}

__global__ __launch_bounds__(256) void k_red(const int* __restrict__ cnt, int n,
                                             int* __restrict__ bsum) {
    __shared__ int ws[4];
    const int tid = threadIdx.x;
    const int base = blockIdx.x * 2048 + tid * 8;
    int s = 0;
    #pragma unroll
    for (int k = 0; k < 8; ++k) { int i = base + k; s += (i < n) ? cnt[i] : 0; }
    #pragma unroll
    for (int off = 32; off; off >>= 1) s += __shfl_down(s, off);
    if ((tid & 63) == 0) ws[tid >> 6] = s;
    __syncthreads();
    if (tid == 0) bsum[blockIdx.x] = ws[0] + ws[1] + ws[2] + ws[3];
}

__global__ void k_scanb(int* __restrict__ b, int nb) {   // nb <= 64
    __shared__ int s[64];
    const int tid = threadIdx.x;
    if (tid < nb) s[tid] = b[tid];
    __syncthreads();
    if (tid == 0) {
        int run = 0;
        for (int i = 0; i < nb; ++i) { int c = s[i]; s[i] = run; run += c; }
    }
    __syncthreads();
    if (tid < nb) b[tid] = s[tid];
}

__global__ __launch_bounds__(256) void k_fill_rs(const int* __restrict__ cnt, int n,
                                                 const int* __restrict__ boff,
                                                 int* __restrict__ rs, int* __restrict__ cur) {
    __shared__ int ts[256];
    const int tid = threadIdx.x;
    const int base = blockIdx.x * 2048 + tid * 8;
    int v[8]; int s = 0;
    #pragma unroll
    for (int k = 0; k < 8; ++k) { int i = base + k; v[k] = (i < n) ? cnt[i] : 0; s += v[k]; }
    ts[tid] = s;
    __syncthreads();
    for (int off = 1; off < 256; off <<= 1) {
        int t = (tid >= off) ? ts[tid - off] : 0;
        __syncthreads();
        ts[tid] += t;
        __syncthreads();
    }
    int ex = boff[blockIdx.x] + ((tid == 0) ? 0 : ts[tid - 1]);
    #pragma unroll
    for (int k = 0; k < 8; ++k) {
        int i = base + k;
        if (i < n) {
            rs[i] = ex; cur[i] = ex; ex += v[k];
            if (i == n - 1) rs[n] = ex;
        }
    }
}

__global__ void k_fill(const int* __restrict__ idx, int n, int* __restrict__ cur,
                       int* __restrict__ perm) {
    int i = blockIdx.x * 256 + threadIdx.x;
    if (i < n) perm[atomicAdd(&cur[idx[i]], 1)] = i;
}

__global__ void k_fill_trip(const int* __restrict__ idx_ji, const int* __restrict__ idx_kj,
                            int n, int* __restrict__ cur,
                            int* __restrict__ kjs, int* __restrict__ rank) {
    int i = blockIdx.x * 256 + threadIdx.x;
    if (i < n) {
        int pos = atomicAdd(&cur[idx_ji[i]], 1);
        kjs[pos] = idx_kj[i];
        rank[i]  = pos;
    }
}

// ---------------------------------------------------------------------------
// Pack interaction weights into MFMA fragment order, split bf16.
// ---------------------------------------------------------------------------
__global__ __launch_bounds__(256) void k_pack(
    const float* __restrict__ Wi_ji, const float* __restrict__ Wi_kj,
    const float* __restrict__ Wi_down,
    const float* __restrict__ Wi_up, const float* __restrict__ Wi_res,
    const float* __restrict__ Wi_lin,
    short* __restrict__ wh, short* __restrict__ wl)
{
    const int g = blockIdx.x * 256 + threadIdx.x;
    if (g >= 2 * PKB) return;
    const int b = g / PKB;
    const int off = g % PKB;
    const float* W;
    int rel, NT;
    if (off < 16384)      { W = Wi_ji   + (size_t)b * 16384; rel = off;          NT = 8; }
    else if (off < 32768) { W = Wi_kj   + (size_t)b * 16384; rel = off - 16384;  NT = 8; }
    else if (off < 40960) { W = Wi_down + (size_t)b * 8192;  rel = off - 32768;  NT = 4; }
    else if (off < 49152) { W = Wi_up   + (size_t)b * 8192;  rel = off - 40960;  NT = 8; }
    else {
        const int i = (off - 49152) / 16384;
        rel = (off - 49152) % 16384;
        NT = 8;
        if (i == 2) W = Wi_lin + (size_t)b * 16384;
        else {
            const int idx = (i < 2) ? i : i - 1;
            W = Wi_res + (size_t)((b * 3 + idx / 2) * 2 + (idx & 1)) * 16384;
        }
    }
    const int j = rel & 7, lane = (rel >> 3) & 63, q = rel >> 9;
    const int nt = q % NT, kt = q / NT;
    const int k = kt * 32 + (lane >> 4) * 8 + j;
    const int n = nt * 16 + (lane & 15);
    const float x = W[(size_t)k * (NT * 16) + n];
    const unsigned short h = bf16_rn(x);
    wh[g] = (short)h;
    wl[g] = (short)bf16_rn(x - bf16_f(h));
}

// Pack output-chain weights (3 out-blocks): [Wup 128x256 | Wlin 3x 256x256]
__global__ __launch_bounds__(256) void k_packo(
    const float* __restrict__ Wo_up, const float* __restrict__ Wo_lin,
    short* __restrict__ wh, short* __restrict__ wl)
{
    const int g = blockIdx.x * 256 + threadIdx.x;
    if (g >= 3 * OPKB) return;
    const int b = g / OPKB;
    const int off = g % OPKB;
    const float* W;
    int rel;
    if (off < 32768) { W = Wo_up + (size_t)b * 32768; rel = off; }
    else {
        const int l = (off - 32768) / 65536;
        rel = (off - 32768) % 65536;
        W = Wo_lin + (size_t)(b * 3 + l) * 65536;
    }
    const int j = rel & 7, lane = (rel >> 3) & 63, q = rel >> 9;
    const int nt = q % 16, kt = q / 16;
    const int k = kt * 32 + (lane >> 4) * 8 + j;
    const int n = nt * 16 + (lane & 15);
    const float x = W[(size_t)k * 256 + n];
    const unsigned short h = bf16_rn(x);
    wh[g] = (short)h;
    wl[g] = (short)bf16_rn(x - bf16_f(h));
}

// ---------------------------------------------------------------------------
// Both blocks' sbf projections in ONE pass over sbf (float4-staged)
// ---------------------------------------------------------------------------
__global__ __launch_bounds__(256) void k_sbfproj2(
    const float* __restrict__ sbf, const float* __restrict__ W1a,
    const float* __restrict__ W1b, const int* __restrict__ rank,
    float* __restrict__ ta, float* __restrict__ tb)
{
    __shared__ float s_sbf[32 * SR];
    __shared__ float s_Wa[SR * BE];
    __shared__ float s_Wb[SR * BE];
    const int tid = threadIdx.x;
    const int t0  = blockIdx.x * 32;
    for (int i = tid; i < SR * BE; i += 256) { s_Wa[i] = W1a[i]; s_Wb[i] = W1b[i]; }
    {
        const float4* sb04 = reinterpret_cast<const float4*>(sbf + (size_t)t0 * SR);
        float4* s4 = reinterpret_cast<float4*>(s_sbf);
        for (int i = tid; i < 32 * SR / 4; i += 256) s4[i] = sb04[i];
    }
    __syncthreads();
    const int tt = tid >> 3, j = tid & 7;
    float sa = 0.0f, sb = 0.0f;
    #pragma unroll
    for (int i = 0; i < SR; ++i) {
        const float v = s_sbf[tt * SR + i];
        sa = fmaf(v, s_Wa[i * BE + j], sa);
        sb = fmaf(v, s_Wb[i * BE + j], sb);
    }
    const size_t p = (size_t)rank[t0 + tt] * BE + j;
    ta[p] = sa;
    tb[p] = sb;
}

// ---------------------------------------------------------------------------
// MFMA fused front (64-row tile, split-bf16, operand-swapped, 2m x 4n split)
// ---------------------------------------------------------------------------
__global__ __launch_bounds__(256, 4) void k_front_mfma(
    const float* __restrict__ xe, const float* __restrict__ rbf,
    const short* __restrict__ wh, const short* __restrict__ wl,
    const float* __restrict__ bji, const float* __restrict__ bkj,
    const float* __restrict__ W1, const float* __restrict__ W2,
    float* __restrict__ xji, float* __restrict__ down)
{
    __shared__ short Ah[64 * 136];
    __shared__ short Al[64 * 136];
    __shared__ float s_tj[64 * 8];
    const int tid = threadIdx.x;
    const int r0  = blockIdx.x * 64;
    const int lane = tid & 63, wv = tid >> 6;
    const int lo4 = lane & 15, hi4 = lane >> 4;
    const int mh = wv >> 1, nh = wv & 1;

    {
        const float4* XG = reinterpret_cast<const float4*>(xe);
        for (int i = tid; i < 64 * 32; i += 256) {
            const int row = i >> 5, c4 = i & 31;
            const float4 v = XG[(size_t)(r0 + row) * 32 + c4];
            unsigned h0, l0, h1, l1;
            pack2(v.x, v.y, h0, l0);
            pack2(v.z, v.w, h1, l1);
            *reinterpret_cast<uint2*>(&Ah[row * 136 + c4 * 4]) = make_uint2(h0, h1);
            *reinterpret_cast<uint2*>(&Al[row * 136 + c4 * 4]) = make_uint2(l0, l1);
        }
    }
    for (int i = tid; i < 64 * 8; i += 256) {
        const int row = i >> 3, j = i & 7;
        const float* rr_ = rbf + (size_t)(r0 + row) * R;
        float s = 0.0f;
        #pragma unroll
        for (int q = 0; q < R; ++q) s = fmaf(rr_[q], W1[q * BE + j], s);
        s_tj[i] = s;
    }
    __syncthreads();

    f32x4 acc[2][4], car[2][4];

    // wave wv owns edges [mh*32, mh*32+32) x feats [nh*64, nh*64+64)
    auto gemm = [&](const short* Wh, const short* Wl) {
        #pragma unroll
        for (int m = 0; m < 2; ++m)
            #pragma unroll
            for (int n = 0; n < 4; ++n) acc[m][n] = (f32x4)0.0f;
        for (int kt = 0; kt < 4; ++kt) {
            bf16x8 xh[2], xl[2], whf[4], wlf[4];
            #pragma unroll
            for (int m = 0; m < 2; ++m) {
                const int off = ((mh * 2 + m) * 16 + lo4) * 136 + kt * 32 + hi4 * 8;
                xh[m] = *reinterpret_cast<const bf16x8*>(&Ah[off]);
                xl[m] = *reinterpret_cast<const bf16x8*>(&Al[off]);
            }
            #pragma unroll
            for (int n = 0; n < 4; ++n) {
                const size_t boff = ((size_t)((kt * 8 + nh * 4 + n) * 64) + lane) * 8;
                whf[n] = *reinterpret_cast<const bf16x8*>(&Wh[boff]);
                wlf[n] = *reinterpret_cast<const bf16x8*>(&Wl[boff]);
            }
            #pragma unroll
            for (int m = 0; m < 2; ++m)
                #pragma unroll
                for (int n = 0; n < 4; ++n) {
                    acc[m][n] = __builtin_amdgcn_mfma_f32_16x16x32_bf16(whf[n], xh[m], acc[m][n], 0, 0, 0);
                    acc[m][n] = __builtin_amdgcn_mfma_f32_16x16x32_bf16(wlf[n], xh[m], acc[m][n], 0, 0, 0);
                    acc[m][n] = __builtin_amdgcn_mfma_f32_16x16x32_bf16(whf[n], xl[m], acc[m][n], 0, 0, 0);
                }
        }
    };

    // p0: xji = silu(xe@Wji + bji)
    gemm(wh, wl);
    #pragma unroll
    for (int n = 0; n < 4; ++n) {
        const int feat0 = (nh * 4 + n) * 16 + hi4 * 4;
        const float4 bj = *reinterpret_cast<const float4*>(&bji[feat0]);
        #pragma unroll
        for (int m = 0; m < 2; ++m) {
            const int edge = r0 + (mh * 2 + m) * 16 + lo4;
            float4 o = make_float4(silu_f(acc[m][n][0] + bj.x), silu_f(acc[m][n][1] + bj.y),
                                   silu_f(acc[m][n][2] + bj.z), silu_f(acc[m][n][3] + bj.w));
            *reinterpret_cast<float4*>(&xji[(size_t)edge * 128 + feat0]) = o;
        }
    }

    // p1: car = silu(xe@Wkj + bkj) .* rb
    gemm(wh + 16384, wl + 16384);
    #pragma unroll
    for (int n = 0; n < 4; ++n) {
        const int feat0 = (nh * 4 + n) * 16 + hi4 * 4;
        const float4 bk = *reinterpret_cast<const float4*>(&bkj[feat0]);
        float4 w2v[8];
        #pragma unroll
        for (int j = 0; j < 8; ++j)
            w2v[j] = *reinterpret_cast<const float4*>(&W2[j * 128 + feat0]);
        #pragma unroll
        for (int m = 0; m < 2; ++m) {
            const int erow = (mh * 2 + m) * 16 + lo4;
            const float4 t0 = *reinterpret_cast<const float4*>(&s_tj[erow * 8]);
            const float4 t1 = *reinterpret_cast<const float4*>(&s_tj[erow * 8 + 4]);
            float rb0 = 0, rb1 = 0, rb2 = 0, rb3 = 0;
            const float tj[8] = {t0.x, t0.y, t0.z, t0.w, t1.x, t1.y, t1.z, t1.w};
            #pragma unroll
            for (int j = 0; j < 8; ++j) {
                rb0 = fmaf(tj[j], w2v[j].x, rb0); rb1 = fmaf(tj[j], w2v[j].y, rb1);
                rb2 = fmaf(tj[j], w2v[j].z, rb2); rb3 = fmaf(tj[j], w2v[j].w, rb3);
            }
            car[m][n][0] = silu_f(acc[m][n][0] + bk.x) * rb0;
            car[m][n][1] = silu_f(acc[m][n][1] + bk.y) * rb1;
            car[m][n][2] = silu_f(acc[m][n][2] + bk.z) * rb2;
            car[m][n][3] = silu_f(acc[m][n][3] + bk.w) * rb3;
        }
    }
    __syncthreads();
    #pragma unroll
    for (int m = 0; m < 2; ++m) {
        const int edge = (mh * 2 + m) * 16 + lo4;
        #pragma unroll
        for (int n = 0; n < 4; ++n) {
            const int feat0 = (nh * 4 + n) * 16 + hi4 * 4;
            unsigned h0, l0, h1, l1;
            pack2(car[m][n][0], car[m][n][1], h0, l0);
            pack2(car[m][n][2], car[m][n][3], h1, l1);
            *reinterpret_cast<uint2*>(&Ah[edge * 136 + feat0]) = make_uint2(h0, h1);
            *reinterpret_cast<uint2*>(&Al[edge * 136 + feat0]) = make_uint2(l0, l1);
        }
    }
    __syncthreads();

    // p2: down = silu(A @ Wdown)  (N=64: wave owns 2m x 2n)
    {
        const short* Wh = wh + 32768;
        const short* Wl = wl + 32768;
        f32x4 a2[2][2];
        #pragma unroll
        for (int m = 0; m < 2; ++m)
            #pragma unroll
            for (int n = 0; n < 2; ++n) a2[m][n] = (f32x4)0.0f;
        for (int kt = 0; kt < 4; ++kt) {
            bf16x8 xh[2], xl[2], whf[2], wlf[2];
            #pragma unroll
            for (int m = 0; m < 2; ++m) {
                const int off = ((mh * 2 + m) * 16 + lo4) * 136 + kt * 32 + hi4 * 8;
                xh[m] = *reinterpret_cast<const bf16x8*>(&Ah[off]);
                xl[m] = *reinterpret_cast<const bf16x8*>(&Al[off]);
            }
            #pragma unroll
            for (int n = 0; n < 2; ++n) {
                const size_t boff = ((size_t)((kt * 4 + nh * 2 + n) * 64) + lane) * 8;
                whf[n] = *reinterpret_cast<const bf16x8*>(&Wh[boff]);
                wlf[n] = *reinterpret_cast<const bf16x8*>(&Wl[boff]);
            }
            #pragma unroll
            for (int m = 0; m < 2; ++m)
                #pragma unroll
                for (int n = 0; n < 2; ++n) {
                    a2[m][n] = __builtin_amdgcn_mfma_f32_16x16x32_bf16(whf[n], xh[m], a2[m][n], 0, 0, 0);
                    a2[m][n] = __builtin_amdgcn_mfma_f32_16x16x32_bf16(wlf[n], xh[m], a2[m][n], 0, 0, 0);
                    a2[m][n] = __builtin_amdgcn_mfma_f32_16x16x32_bf16(whf[n], xl[m], a2[m][n], 0, 0, 0);
                }
        }
        #pragma unroll
        for (int n = 0; n < 2; ++n) {
            const int feat0 = (nh * 2 + n) * 16 + hi4 * 4;
            #pragma unroll
            for (int m = 0; m < 2; ++m) {
                const int edge = r0 + (mh * 2 + m) * 16 + lo4;
                *reinterpret_cast<float4*>(&down[(size_t)edge * 64 + feat0]) =
                    make_float4(silu_f(a2[m][n][0]), silu_f(a2[m][n][1]),
                                silu_f(a2[m][n][2]), silu_f(a2[m][n][3]));
            }
        }
    }
}

// ---------------------------------------------------------------------------
// Edge aggregation over sorted triplets (one wave per edge, 4-deep unroll)
// ---------------------------------------------------------------------------
__global__ __launch_bounds__(256) void k_agg(
    const int* __restrict__ rs, const int* __restrict__ kjs,
    const float* __restrict__ tmps, const float* __restrict__ down,
    const float* __restrict__ W2, float* __restrict__ agg)
{
    const int w = threadIdx.x >> 6, lane = threadIdx.x & 63;
    const int e = blockIdx.x * 4 + w;
    float w2[BE];
    #pragma unroll
    for (int j = 0; j < BE; ++j) w2[j] = W2[j * INTD + lane];

    const float4* tmps4 = reinterpret_cast<const float4*>(tmps);
    const int lo = rs[e], hi = rs[e + 1];
    float acc = 0.0f;
    int idx = lo;
    for (; idx + 3 < hi; idx += 4) {
        const int k0 = kjs[idx], k1 = kjs[idx + 1], k2 = kjs[idx + 2], k3 = kjs[idx + 3];
        const float4 a0 = tmps4[2*idx],   a1 = tmps4[2*idx+1];
        const float4 b0 = tmps4[2*idx+2], b1 = tmps4[2*idx+3];
        const float4 c0 = tmps4[2*idx+4], c1 = tmps4[2*idx+5];
        const float4 d0 = tmps4[2*idx+6], d1 = tmps4[2*idx+7];
        const float g0 = down[(size_t)k0 * INTD + lane];
        const float g1 = down[(size_t)k1 * INTD + lane];
        const float g2 = down[(size_t)k2 * INTD + lane];
        const float g3 = down[(size_t)k3 * INTD + lane];
        float s0 = a0.x*w2[0] + a0.y*w2[1] + a0.z*w2[2] + a0.w*w2[3]
                 + a1.x*w2[4] + a1.y*w2[5] + a1.z*w2[6] + a1.w*w2[7];
        float s1 = b0.x*w2[0] + b0.y*w2[1] + b0.z*w2[2] + b0.w*w2[3]
                 + b1.x*w2[4] + b1.y*w2[5] + b1.z*w2[6] + b1.w*w2[7];
        float s2 = c0.x*w2[0] + c0.y*w2[1] + c0.z*w2[2] + c0.w*w2[3]
                 + c1.x*w2[4] + c1.y*w2[5] + c1.z*w2[6] + c1.w*w2[7];
        float s3 = d0.x*w2[0] + d0.y*w2[1] + d0.z*w2[2] + d0.w*w2[3]
                 + d1.x*w2[4] + d1.y*w2[5] + d1.z*w2[6] + d1.w*w2[7];
        acc = fmaf(g0, s0, acc);
        acc = fmaf(g1, s1, acc);
        acc = fmaf(g2, s2, acc);
        acc = fmaf(g3, s3, acc);
    }
    for (; idx < hi; ++idx) {
        const int kj = kjs[idx];
        const float4 a0 = tmps4[2 * idx], a1 = tmps4[2 * idx + 1];
        const float d = down[(size_t)kj * INTD + lane];
        float sa = a0.x*w2[0] + a0.y*w2[1] + a0.z*w2[2] + a0.w*w2[3]
                 + a1.x*w2[4] + a1.y*w2[5] + a1.z*w2[6] + a1.w*w2[7];
        acc = fmaf(d, sa, acc);
    }
    agg[(size_t)e * INTD + lane] = acc;
}

// ---------------------------------------------------------------------------
// MFMA fused tail (64-row tile, split-bf16, operand-swapped, 2m x 4n split)
// ---------------------------------------------------------------------------
__global__ __launch_bounds__(256, 4) void k_tail_mfma(
    const float* __restrict__ agg, const float* __restrict__ xji,
    const float* __restrict__ xe,
    const short* __restrict__ wh, const short* __restrict__ wl,
    const float* __restrict__ br, const float* __restrict__ blin,
    float* __restrict__ out)
{
    __shared__ short Ah[64 * 136];
    __shared__ short Al[64 * 136];
    const int tid = threadIdx.x;
    const int r0  = blockIdx.x * 64;
    const int lane = tid & 63, wv = tid >> 6;
    const int lo4 = lane & 15, hi4 = lane >> 4;
    const int mh = wv >> 1, nh = wv & 1;

    {
        const float4* AG = reinterpret_cast<const float4*>(agg);
        for (int i = tid; i < 64 * 16; i += 256) {
            const int row = i >> 4, c4 = i & 15;
            const float4 v = AG[(size_t)(r0 + row) * 16 + c4];
            unsigned h0, l0, h1, l1;
            pack2(v.x, v.y, h0, l0);
            pack2(v.z, v.w, h1, l1);
            *reinterpret_cast<uint2*>(&Ah[row * 136 + c4 * 4]) = make_uint2(h0, h1);
            *reinterpret_cast<uint2*>(&Al[row * 136 + c4 * 4]) = make_uint2(l0, l1);
        }
    }
    __syncthreads();

    f32x4 acc[2][4], car[2][4];

    auto gemm = [&](const short* Wh, const short* Wl, int nkt) {
        #pragma unroll
        for (int m = 0; m < 2; ++m)
            #pragma unroll
            for (int n = 0; n < 4; ++n) acc[m][n] = (f32x4)0.0f;
        for (int kt = 0; kt < nkt; ++kt) {
            bf16x8 xh[2], xl[2], whf[4], wlf[4];
            #pragma unroll
            for (int m = 0; m < 2; ++m) {
                const int off = ((mh * 2 + m) * 16 + lo4) * 136 + kt * 32 + hi4 * 8;
                xh[m] = *reinterpret_cast<const bf16x8*>(&Ah[off]);
                xl[m] = *reinterpret_cast<const bf16x8*>(&Al[off]);
            }
            #pragma unroll
            for (int n = 0; n < 4; ++n) {
                const size_t boff = ((size_t)((kt * 8 + nh * 4 + n) * 64) + lane) * 8;
                whf[n] = *reinterpret_cast<const bf16x8*>(&Wh[boff]);
                wlf[n] = *reinterpret_cast<const bf16x8*>(&Wl[boff]);
            }
            #pragma unroll
            for (int m = 0; m < 2; ++m)
                #pragma unroll
                for (int n = 0; n < 4; ++n) {
                    acc[m][n] = __builtin_amdgcn_mfma_f32_16x16x32_bf16(whf[n], xh[m], acc[m][n], 0, 0, 0);
                    acc[m][n] = __builtin_amdgcn_mfma_f32_16x16x32_bf16(wlf[n], xh[m], acc[m][n], 0, 0, 0);
                    acc[m][n] = __builtin_amdgcn_mfma_f32_16x16x32_bf16(whf[n], xl[m], acc[m][n], 0, 0, 0);
                }
        }
    };

    auto wrA = [&](f32x4 v[2][4]) {
        __syncthreads();
        #pragma unroll
        for (int m = 0; m < 2; ++m) {
            const int edge = (mh * 2 + m) * 16 + lo4;
            #pragma unroll
            for (int n = 0; n < 4; ++n) {
                const int feat0 = (nh * 4 + n) * 16 + hi4 * 4;
                unsigned h0, l0, h1, l1;
                pack2(v[m][n][0], v[m][n][1], h0, l0);
                pack2(v[m][n][2], v[m][n][3], h1, l1);
                *reinterpret_cast<uint2*>(&Ah[edge * 136 + feat0]) = make_uint2(h0, h1);
                *reinterpret_cast<uint2*>(&Al[edge * 136 + feat0]) = make_uint2(l0, l1);
            }
        }
        __syncthreads();
    };

    // p0: car = silu(agg@Wup) + xji
    gemm(wh, wl, 2);
    #pragma unroll
    for (int n = 0; n < 4; ++n) {
        const int feat0 = (nh * 4 + n) * 16 + hi4 * 4;
        #pragma unroll
        for (int m = 0; m < 2; ++m) {
            const int edge = r0 + (mh * 2 + m) * 16 + lo4;
            const float4 xv = *reinterpret_cast<const float4*>(&xji[(size_t)edge * 128 + feat0]);
            car[m][n][0] = silu_f(acc[m][n][0]) + xv.x;
            car[m][n][1] = silu_f(acc[m][n][1]) + xv.y;
            car[m][n][2] = silu_f(acc[m][n][2]) + xv.z;
            car[m][n][3] = silu_f(acc[m][n][3]) + xv.w;
        }
    }
    wrA(car);

    auto tphase = [&](const short* Wh, const short* Wl, const float* bias) {
        gemm(Wh, Wl, 4);
        #pragma unroll
        for (int n = 0; n < 4; ++n) {
            const int feat0 = (nh * 4 + n) * 16 + hi4 * 4;
            const float4 bv = *reinterpret_cast<const float4*>(&bias[feat0]);
            #pragma unroll
            for (int m = 0; m < 2; ++m) {
                acc[m][n][0] = silu_f(acc[m][n][0] + bv.x);
                acc[m][n][1] = silu_f(acc[m][n][1] + bv.y);
                acc[m][n][2] = silu_f(acc[m][n][2] + bv.z);
                acc[m][n][3] = silu_f(acc[m][n][3] + bv.w);
            }
        }
        wrA(acc);
    };
    auto cphase = [&](const short* Wh, const short* Wl, const float* bias) {
        gemm(Wh, Wl, 4);
        #pragma unroll
        for (int n = 0; n < 4; ++n) {
            const int feat0 = (nh * 4 + n) * 16 + hi4 * 4;
            const float4 bv = *reinterpret_cast<const float4*>(&bias[feat0]);
            #pragma unroll
            for (int m = 0; m < 2; ++m) {
                car[m][n][0] += silu_f(acc[m][n][0] + bv.x);
                car[m][n][1] += silu_f(acc[m][n][1] + bv.y);
                car[m][n][2] += silu_f(acc[m][n][2] + bv.z);
                car[m][n][3] += silu_f(acc[m][n][3] + bv.w);
            }
        }
        wrA(car);
    };

    tphase(wh + 8192,              wl + 8192,              br + 0 * 128);   // W0
    cphase(wh + 8192 + 16384,      wl + 8192 + 16384,      br + 1 * 128);   // W1

    // p3: car = silu(acc + blin) + xe
    gemm(wh + 8192 + 2 * 16384, wl + 8192 + 2 * 16384, 4);
    #pragma unroll
    for (int n = 0; n < 4; ++n) {
        const int feat0 = (nh * 4 + n) * 16 + hi4 * 4;
        const float4 bv = *reinterpret_cast<const float4*>(&blin[feat0]);
        #pragma unroll
        for (int m = 0; m < 2; ++m) {
            const int edge = r0 + (mh * 2 + m) * 16 + lo4;
            const float4 xv = *reinterpret_cast<const float4*>(&xe[(size_t)edge * 128 + feat0]);
            car[m][n][0] = silu_f(acc[m][n][0] + bv.x) + xv.x;
            car[m][n][1] = silu_f(acc[m][n][1] + bv.y) + xv.y;
            car[m][n][2] = silu_f(acc[m][n][2] + bv.z) + xv.z;
            car[m][n][3] = silu_f(acc[m][n][3] + bv.w) + xv.w;
        }
    }
    wrA(car);

    tphase(wh + 8192 + 3 * 16384, wl + 8192 + 3 * 16384, br + 2 * 128);     // W2
    cphase(wh + 8192 + 4 * 16384, wl + 8192 + 4 * 16384, br + 3 * 128);     // W3
    tphase(wh + 8192 + 5 * 16384, wl + 8192 + 5 * 16384, br + 4 * 128);     // W4

    // p7: out = car + silu(acc + b5)
    gemm(wh + 8192 + 6 * 16384, wl + 8192 + 6 * 16384, 4);
    #pragma unroll
    for (int n = 0; n < 4; ++n) {
        const int feat0 = (nh * 4 + n) * 16 + hi4 * 4;
        const float4 bv = *reinterpret_cast<const float4*>(&br[5 * 128 + feat0]);
        #pragma unroll
        for (int m = 0; m < 2; ++m) {
            const int edge = r0 + (mh * 2 + m) * 16 + lo4;
            float4 o = make_float4(car[m][n][0] + silu_f(acc[m][n][0] + bv.x),
                                   car[m][n][1] + silu_f(acc[m][n][1] + bv.y),
                                   car[m][n][2] + silu_f(acc[m][n][2] + bv.z),
                                   car[m][n][3] + silu_f(acc[m][n][3] + bv.w));
            *reinterpret_cast<float4*>(&out[(size_t)edge * 128 + feat0]) = o;
        }
    }
}

// ---------------------------------------------------------------------------
// Node aggregation (CSR over edge_i)
// ---------------------------------------------------------------------------
__global__ __launch_bounds__(256) void k_nodes(
    const int* __restrict__ rs, const int* __restrict__ perm,
    const float* __restrict__ rbf, const float* __restrict__ Wrbf,
    const float* __restrict__ xe, float* __restrict__ nodes)
{
    const int tid = threadIdx.x;
    const int n = blockIdx.x * 2 + (tid >> 7);
    const int c = tid & (H - 1);
    float wr[R];
    #pragma unroll
    for (int i = 0; i < R; ++i) wr[i] = Wrbf[i * H + c];
    float acc = 0.0f;
    const int lo = rs[n], hi = rs[n + 1];
    for (int idx = lo; idx < hi; ++idx) {
        const int e = perm[idx];
        const float* rb = rbf + (size_t)e * R;
        float g = 0.0f;
        #pragma unroll
        for (int i = 0; i < R; ++i) g = fmaf(rb[i], wr[i], g);
        acc = fmaf(g, xe[(size_t)e * H + c], acc);
    }
    nodes[(size_t)n * H + c] = acc;
}

// ---------------------------------------------------------------------------
// MFMA output chain (16-node tile, split-bf16, operand-swapped)
// ---------------------------------------------------------------------------
__global__ __launch_bounds__(256, 4) void k_outchain_mfma(
    const float* __restrict__ nodes, const short* __restrict__ wh,
    const short* __restrict__ wl, const float* __restrict__ bup,
    const float* __restrict__ blin, const float* __restrict__ Wout,
    float* __restrict__ P)
{
    __shared__ short Ah[16 * 264];
    __shared__ short Al[16 * 264];
    __shared__ float red[16 * 17];
    const int tid = threadIdx.x;
    const int n0  = blockIdx.x * 16;
    const int lane = tid & 63, wv = tid >> 6;
    const int lo4 = lane & 15, hi4 = lane >> 4;

    {
        const float4* NG = reinterpret_cast<const float4*>(nodes);
        for (int i = tid; i < 16 * 32; i += 256) {
            const int row = i >> 5, c4 = i & 31;
            const float4 v = NG[(size_t)(n0 + row) * 32 + c4];
            unsigned h0, l0, h1, l1;
            pack2(v.x, v.y, h0, l0);
            pack2(v.z, v.w, h1, l1);
            *reinterpret_cast<uint2*>(&Ah[row * 264 + c4 * 4]) = make_uint2(h0, h1);
            *reinterpret_cast<uint2*>(&Al[row * 264 + c4 * 4]) = make_uint2(l0, l1);
        }
    }
    __syncthreads();

    f32x4 acc[4];

    auto gemm = [&](const short* Wh, const short* Wl, int nkt) {
        #pragma unroll
        for (int n = 0; n < 4; ++n) acc[n] = (f32x4)0.0f;
        for (int kt = 0; kt < nkt; ++kt) {
            bf16x8 xh, xl, whf[4], wlf[4];
            {
                const int off = lo4 * 264 + kt * 32 + hi4 * 8;
                xh = *reinterpret_cast<const bf16x8*>(&Ah[off]);
                xl = *reinterpret_cast<const bf16x8*>(&Al[off]);
            }
            #pragma unroll
            for (int n = 0; n < 4; ++n) {
                const size_t boff = ((size_t)((kt * 16 + wv * 4 + n) * 64) + lane) * 8;
                whf[n] = *reinterpret_cast<const bf16x8*>(&Wh[boff]);
                wlf[n] = *reinterpret_cast<const bf16x8*>(&Wl[boff]);
            }
            #pragma unroll
            for (int n = 0; n < 4; ++n) {
                acc[n] = __builtin_amdgcn_mfma_f32_16x16x32_bf16(whf[n], xh, acc[n], 0, 0, 0);
                acc[n] = __builtin_amdgcn_mfma_f32_16x16x32_bf16(wlf[n], xh, acc[n], 0, 0, 0);
                acc[n] = __builtin_amdgcn_mfma_f32_16x16x32_bf16(whf[n], xl, acc[n], 0, 0, 0);
            }
        }
    };

    auto wrA = [&](bool dosilu, const float* bias) {
        __syncthreads();
        const int node = lo4;
        #pragma unroll
        for (int n = 0; n < 4; ++n) {
            const int feat0 = (wv * 4 + n) * 16 + hi4 * 4;
            const float4 bv = *reinterpret_cast<const float4*>(&bias[feat0]);
            float v0 = acc[n][0] + bv.x, v1 = acc[n][1] + bv.y;
            float v2 = acc[n][2] + bv.z, v3 = acc[n][3] + bv.w;
            if (dosilu) { v0 = silu_f(v0); v1 = silu_f(v1); v2 = silu_f(v2); v3 = silu_f(v3); }
            unsigned h0, l0, h1, l1;
            pack2(v0, v1, h0, l0);
            pack2(v2, v3, h1, l1);
            *reinterpret_cast<uint2*>(&Ah[node * 264 + feat0]) = make_uint2(h0, h1);
            *reinterpret_cast<uint2*>(&Al[node * 264 + feat0]) = make_uint2(l0, l1);
        }
        __syncthreads();
    };

    gemm(wh, wl, 4);                                   // nodes @ Wup (K=128)
    wrA(false, bup);
    gemm(wh + 32768, wl + 32768, 8);                   // @ Wl0 (K=256)
    wrA(true, blin + 0 * OE);
    gemm(wh + 32768 + 65536, wl + 32768 + 65536, 8);   // @ Wl1
    wrA(true, blin + 1 * OE);
    gemm(wh + 32768 + 2 * 65536, wl + 32768 + 2 * 65536, 8);  // @ Wl2

    // epilogue: t = silu(acc + b2); partial = t . Wout; reduce per node
    float part = 0.0f;
    #pragma unroll
    for (int n = 0; n < 4; ++n) {
        const int feat0 = (wv * 4 + n) * 16 + hi4 * 4;
        const float4 bv = *reinterpret_cast<const float4*>(&blin[2 * OE + feat0]);
        const float4 wo = *reinterpret_cast<const float4*>(&Wout[feat0]);
        part += silu_f(acc[n][0] + bv.x) * wo.x
              + silu_f(acc[n][1] + bv.y) * wo.y
              + silu_f(acc[n][2] + bv.z) * wo.z
              + silu_f(acc[n][3] + bv.w) * wo.w;
    }
    red[lo4 * 17 + wv * 4 + hi4] = part;
    __syncthreads();
    if (tid < 16) {
        float s = 0.0f;
        #pragma unroll
        for (int c = 0; c < 16; ++c) s += red[tid * 17 + c];
        P[n0 + tid] += s;
    }
}

// ---------------------------------------------------------------------------
extern "C" void kernel_launch(void* const* d_in, const int* in_sizes, int n_in,
                              void* d_out, int out_size, void* d_ws, size_t ws_size,
                              hipStream_t stream)
{
    (void)in_sizes; (void)n_in; (void)out_size; (void)ws_size;

    const float* x       = (const float*)d_in[0];
    const float* dist    = (const float*)d_in[1];
    const float* freq    = (const float*)d_in[2];
    const float* sbf     = (const float*)d_in[3];
    const int*   idx_kj  = (const int*)d_in[4];
    const int*   idx_ji  = (const int*)d_in[5];
    const int*   edge_i  = (const int*)d_in[6];
    const float* Wi_rbf1 = (const float*)d_in[8];
    const float* Wi_rbf2 = (const float*)d_in[9];
    const float* Wi_sbf1 = (const float*)d_in[10];
    const float* Wi_sbf2 = (const float*)d_in[11];
    const float* Wi_kj   = (const float*)d_in[12];
    const float* bi_kj   = (const float*)d_in[13];
    const float* Wi_ji   = (const float*)d_in[14];
    const float* bi_ji   = (const float*)d_in[15];
    const float* Wi_down = (const float*)d_in[16];
    const float* Wi_up   = (const float*)d_in[17];
    const float* Wi_res  = (const float*)d_in[18];
    const float* bi_res  = (const float*)d_in[19];
    const float* Wi_lin  = (const float*)d_in[20];
    const float* bi_lin  = (const float*)d_in[21];
    const float* Wo_rbf  = (const float*)d_in[22];
    const float* Wo_up   = (const float*)d_in[23];
    const float* bo_up   = (const float*)d_in[24];
    const float* Wo_lin  = (const float*)d_in[25];
    const float* bo_lin  = (const float*)d_in[26];
    const float* Wo_out  = (const float*)d_in[27];
    float* P = (float*)d_out;

    // ---- workspace carve-up ----
    float* w      = (float*)d_ws;
    float* rbf    = w;  w += (size_t)E * R;
    float* xeA    = w;  w += (size_t)E * H;
    float* xeB    = w;  w += (size_t)E * H;
    float* xji    = w;  w += (size_t)E * H;
    float* down   = w;  w += (size_t)E * INTD;
    float* agg    = w;  w += (size_t)E * INTD;
    float* tmp0   = w;  w += (size_t)T * BE;
    float* tmp1   = w;  w += (size_t)T * BE;
    float* nodes  = w;  w += (size_t)NN * H;
    int* ip       = (int*)w;
    int* trip_rs  = ip;  ip += E + 1;
    int* trip_cur = ip;  ip += E;
    int* rank_t   = ip;  ip += T;
    int* kjs      = ip;  ip += T;
    int* edge_rs  = ip;  ip += NN + 1;
    int* edge_cur = ip;  ip += NN;
    int* perm_e   = ip;  ip += E;
    int* bsumT    = ip;  ip += 64;
    int* bsumE    = ip;  ip += 64;
    short* wpk_hi = (short*)ip;
    short* wpk_lo = wpk_hi + 2 * PKB;
    short* wo_hi  = wpk_lo + 2 * PKB;
    short* wo_lo  = wo_hi + 3 * OPKB;

    // ---- CSR build ----
    hipMemsetAsync(trip_cur, 0, (size_t)E * sizeof(int), stream);
    hipMemsetAsync(edge_cur, 0, (size_t)NN * sizeof(int), stream);
    k_count<<<(T + 255) / 256, 256, 0, stream>>>(idx_ji, T, trip_cur);
    k_count<<<(E + 255) / 256, 256, 0, stream>>>(edge_i, E, edge_cur);
    const int nbT = (E + 2047) / 2048, nbE = (NN + 2047) / 2048;
    k_red<<<nbT, 256, 0, stream>>>(trip_cur, E, bsumT);
    k_scanb<<<1, 64, 0, stream>>>(bsumT, nbT);
    k_fill_rs<<<nbT, 256, 0, stream>>>(trip_cur, E, bsumT, trip_rs, trip_cur);
    k_red<<<nbE, 256, 0, stream>>>(edge_cur, NN, bsumE);
    k_scanb<<<1, 64, 0, stream>>>(bsumE, nbE);
    k_fill_rs<<<nbE, 256, 0, stream>>>(edge_cur, NN, bsumE, edge_rs, edge_cur);
    k_fill_trip<<<(T + 255) / 256, 256, 0, stream>>>(idx_ji, idx_kj, T, trip_cur, kjs, rank_t);
    k_fill<<<(E + 255) / 256, 256, 0, stream>>>(edge_i, E, edge_cur, perm_e);

    hipMemsetAsync(d_out, 0, (size_t)NN * sizeof(float), stream);
    k_rbf<<<(E + 255) / 256, 256, 0, stream>>>(dist, freq, rbf);
    k_pack<<<(2 * PKB + 255) / 256, 256, 0, stream>>>(Wi_ji, Wi_kj, Wi_down,
                                                      Wi_up, Wi_res, Wi_lin,
                                                      wpk_hi, wpk_lo);
    k_packo<<<(3 * OPKB + 255) / 256, 256, 0, stream>>>(Wo_up, Wo_lin, wo_hi, wo_lo);
    k_sbfproj2<<<T / 32, 256, 0, stream>>>(sbf, Wi_sbf1, Wi_sbf1 + (size_t)SR * BE,
                                           rank_t, tmp0, tmp1);

    auto out_block = [&](int b, const float* xe) {
        k_nodes<<<NN / 2, 256, 0, stream>>>(edge_rs, perm_e, rbf,
                                            Wo_rbf + (size_t)b * R * H, xe, nodes);
        k_outchain_mfma<<<NN / 16, 256, 0, stream>>>(nodes,
                                                     wo_hi + (size_t)b * OPKB,
                                                     wo_lo + (size_t)b * OPKB,
                                                     bo_up + (size_t)b * OE,
                                                     bo_lin + (size_t)b * 3 * OE,
                                                     Wo_out + (size_t)b * OE, P);
    };

    const int gE64 = E / 64;
    auto interact = [&](int b, const float* xe, const float* tmp, float* out) {
        k_front_mfma<<<gE64, 256, 0, stream>>>(xe, rbf,
                                               wpk_hi + (size_t)b * PKB,
                                               wpk_lo + (size_t)b * PKB,
                                               bi_ji + (size_t)b * H,
                                               bi_kj + (size_t)b * H,
                                               Wi_rbf1 + (size_t)b * R * BE,
                                               Wi_rbf2 + (size_t)b * BE * H,
                                               xji, down);
        k_agg<<<E / 4, 256, 0, stream>>>(trip_rs, kjs, tmp, down,
                                         Wi_sbf2 + (size_t)b * BE * INTD, agg);
        k_tail_mfma<<<gE64, 256, 0, stream>>>(agg, xji, xe,
                                              wpk_hi + (size_t)b * PKB + TAILO,
                                              wpk_lo + (size_t)b * PKB + TAILO,
                                              bi_res + (size_t)b * 3 * 2 * H,
                                              bi_lin + (size_t)b * H, out);
    };

    out_block(0, x);
    interact(0, x, tmp0, xeB);
    out_block(1, xeB);
    interact(1, xeB, tmp1, xeA);
    out_block(2, xeA);
}

// Round 14
// 1318.380 us; speedup vs baseline: 1.1199x; 1.1199x over previous
//
#include <hip/hip_runtime.h>
#include <hip/hip_bf16.h>

// DimeNet++ forward: front/tail/outchain on MFMA (split-bf16, operand-swapped).
// Restored measured-best config (r11 bench, 1336us): tail/front 4m x 2n tiles
// @ launch_bounds(256,4); k_agg 4-deep sequential unroll @ E/4 blocks;
// float4 sbf staging; 16-node outchain.
namespace {
constexpr int E     = 120000;
constexpr int T     = 800000;
constexpr int NN    = 12000;
constexpr int H     = 128;
constexpr int INTD  = 64;
constexpr int BE    = 8;
constexpr int R     = 6;
constexpr int SR    = 42;
constexpr int OE    = 256;
constexpr float CUTOFF = 5.0f;
// packed interaction weights per block:
// [Wji 16384 | Wkj 16384 | Wdown 8192 | Wup 8192 | W0 W1 Wlin W2 W3 W4 W5 7x16384]
constexpr int PKB   = 163840;
constexpr int TAILO = 40960;
// packed output-block weights: [Wup 32768 | Wlin0,1,2 3x65536]
constexpr int OPKB  = 229376;
}

typedef __attribute__((ext_vector_type(8))) short bf16x8;
typedef __attribute__((ext_vector_type(4))) float f32x4;

__device__ __forceinline__ float silu_f(float x) { return x / (1.0f + __expf(-x)); }

__device__ __forceinline__ unsigned fbits(float x) {
    union { float f; unsigned u; } v; v.f = x; return v.u;
}
__device__ __forceinline__ float fof(unsigned u) {
    union { float f; unsigned u; } v; v.u = u; return v.f;
}
__device__ __forceinline__ unsigned short bf16_rn(float x) {
    unsigned u = fbits(x);
    unsigned r = u + 0x7FFFu + ((u >> 16) & 1u);
    return (unsigned short)(r >> 16);
}
__device__ __forceinline__ float bf16_f(unsigned short h) { return fof(((unsigned)h) << 16); }

// truncation split: x = hi + lo; packs two elements' hi into h, lo into l.
__device__ __forceinline__ void pack2(float x0, float x1, unsigned& h, unsigned& l) {
    const unsigned u0 = fbits(x0), u1 = fbits(x1);
    const unsigned t0 = u0 & 0xFFFF0000u, t1 = u1 & 0xFFFF0000u;
    h = (u0 >> 16) | t1;
    l = (fbits(x0 - fof(t0)) >> 16) | (fbits(x1 - fof(t1)) & 0xFFFF0000u);
}

// ---------------------------------------------------------------------------
// rbf[E,6]
// ---------------------------------------------------------------------------
__global__ void k_rbf(const float* __restrict__ dist, const float* __restrict__ freq,
                      float* __restrict__ rbf) {
    int e = blockIdx.x * blockDim.x + threadIdx.x;
    if (e >= E) return;
    float d  = dist[e] * (1.0f / CUTOFF);
    float d2 = d * d;
    float d5 = d2 * d2 * d;
    float env = 1.0f / d - 28.0f * d5 + 48.0f * d5 * d - 21.0f * d5 * d2;
    #pragma unroll
    for (int i = 0; i < R; ++i) rbf[e * R + i] = env * sinf(freq[i] * d);
}

// ---------------------------------------------------------------------------
// CSR build
// ---------------------------------------------------------------------------
__global__ void k_count(const int* __restrict__ idx, int n, int* __restrict__ cnt) {
    int i = blockIdx.x * 256 + threadIdx.x;
    if (i < n) atomicAdd(&cnt[idx[i]], 1);
}

__global__ __launch_bounds__(256) void k_red(const int* __restrict__ cnt, int n,
                                             int* __restrict__ bsum) {
    __shared__ int ws[4];
    const int tid = threadIdx.x;
    const int base = blockIdx.x * 2048 + tid * 8;
    int s = 0;
    #pragma unroll
    for (int k = 0; k < 8; ++k) { int i = base + k; s += (i < n) ? cnt[i] : 0; }
    #pragma unroll
    for (int off = 32; off; off >>= 1) s += __shfl_down(s, off);
    if ((tid & 63) == 0) ws[tid >> 6] = s;
    __syncthreads();
    if (tid == 0) bsum[blockIdx.x] = ws[0] + ws[1] + ws[2] + ws[3];
}

__global__ void k_scanb(int* __restrict__ b, int nb) {   // nb <= 64
    __shared__ int s[64];
    const int tid = threadIdx.x;
    if (tid < nb) s[tid] = b[tid];
    __syncthreads();
    if (tid == 0) {
        int run = 0;
        for (int i = 0; i < nb; ++i) { int c = s[i]; s[i] = run; run += c; }
    }
    __syncthreads();
    if (tid < nb) b[tid] = s[tid];
}

__global__ __launch_bounds__(256) void k_fill_rs(const int* __restrict__ cnt, int n,
                                                 const int* __restrict__ boff,
                                                 int* __restrict__ rs, int* __restrict__ cur) {
    __shared__ int ts[256];
    const int tid = threadIdx.x;
    const int base = blockIdx.x * 2048 + tid * 8;
    int v[8]; int s = 0;
    #pragma unroll
    for (int k = 0; k < 8; ++k) { int i = base + k; v[k] = (i < n) ? cnt[i] : 0; s += v[k]; }
    ts[tid] = s;
    __syncthreads();
    for (int off = 1; off < 256; off <<= 1) {
        int t = (tid >= off) ? ts[tid - off] : 0;
        __syncthreads();
        ts[tid] += t;
        __syncthreads();
    }
    int ex = boff[blockIdx.x] + ((tid == 0) ? 0 : ts[tid - 1]);
    #pragma unroll
    for (int k = 0; k < 8; ++k) {
        int i = base + k;
        if (i < n) {
            rs[i] = ex; cur[i] = ex; ex += v[k];
            if (i == n - 1) rs[n] = ex;
        }
    }
}

__global__ void k_fill(const int* __restrict__ idx, int n, int* __restrict__ cur,
                       int* __restrict__ perm) {
    int i = blockIdx.x * 256 + threadIdx.x;
    if (i < n) perm[atomicAdd(&cur[idx[i]], 1)] = i;
}

__global__ void k_fill_trip(const int* __restrict__ idx_ji, const int* __restrict__ idx_kj,
                            int n, int* __restrict__ cur,
                            int* __restrict__ kjs, int* __restrict__ rank) {
    int i = blockIdx.x * 256 + threadIdx.x;
    if (i < n) {
        int pos = atomicAdd(&cur[idx_ji[i]], 1);
        kjs[pos] = idx_kj[i];
        rank[i]  = pos;
    }
}

// ---------------------------------------------------------------------------
// Pack interaction weights into MFMA fragment order, split bf16.
// ---------------------------------------------------------------------------
__global__ __launch_bounds__(256) void k_pack(
    const float* __restrict__ Wi_ji, const float* __restrict__ Wi_kj,
    const float* __restrict__ Wi_down,
    const float* __restrict__ Wi_up, const float* __restrict__ Wi_res,
    const float* __restrict__ Wi_lin,
    short* __restrict__ wh, short* __restrict__ wl)
{
    const int g = blockIdx.x * 256 + threadIdx.x;
    if (g >= 2 * PKB) return;
    const int b = g / PKB;
    const int off = g % PKB;
    const float* W;
    int rel, NT;
    if (off < 16384)      { W = Wi_ji   + (size_t)b * 16384; rel = off;          NT = 8; }
    else if (off < 32768) { W = Wi_kj   + (size_t)b * 16384; rel = off - 16384;  NT = 8; }
    else if (off < 40960) { W = Wi_down + (size_t)b * 8192;  rel = off - 32768;  NT = 4; }
    else if (off < 49152) { W = Wi_up   + (size_t)b * 8192;  rel = off - 40960;  NT = 8; }
    else {
        const int i = (off - 49152) / 16384;
        rel = (off - 49152) % 16384;
        NT = 8;
        if (i == 2) W = Wi_lin + (size_t)b * 16384;
        else {
            const int idx = (i < 2) ? i : i - 1;
            W = Wi_res + (size_t)((b * 3 + idx / 2) * 2 + (idx & 1)) * 16384;
        }
    }
    const int j = rel & 7, lane = (rel >> 3) & 63, q = rel >> 9;
    const int nt = q % NT, kt = q / NT;
    const int k = kt * 32 + (lane >> 4) * 8 + j;
    const int n = nt * 16 + (lane & 15);
    const float x = W[(size_t)k * (NT * 16) + n];
    const unsigned short h = bf16_rn(x);
    wh[g] = (short)h;
    wl[g] = (short)bf16_rn(x - bf16_f(h));
}

// Pack output-chain weights (3 out-blocks): [Wup 128x256 | Wlin 3x 256x256]
__global__ __launch_bounds__(256) void k_packo(
    const float* __restrict__ Wo_up, const float* __restrict__ Wo_lin,
    short* __restrict__ wh, short* __restrict__ wl)
{
    const int g = blockIdx.x * 256 + threadIdx.x;
    if (g >= 3 * OPKB) return;
    const int b = g / OPKB;
    const int off = g % OPKB;
    const float* W;
    int rel;
    if (off < 32768) { W = Wo_up + (size_t)b * 32768; rel = off; }
    else {
        const int l = (off - 32768) / 65536;
        rel = (off - 32768) % 65536;
        W = Wo_lin + (size_t)(b * 3 + l) * 65536;
    }
    const int j = rel & 7, lane = (rel >> 3) & 63, q = rel >> 9;
    const int nt = q % 16, kt = q / 16;
    const int k = kt * 32 + (lane >> 4) * 8 + j;
    const int n = nt * 16 + (lane & 15);
    const float x = W[(size_t)k * 256 + n];
    const unsigned short h = bf16_rn(x);
    wh[g] = (short)h;
    wl[g] = (short)bf16_rn(x - bf16_f(h));
}

// ---------------------------------------------------------------------------
// Both blocks' sbf projections in ONE pass over sbf (float4-staged)
// ---------------------------------------------------------------------------
__global__ __launch_bounds__(256) void k_sbfproj2(
    const float* __restrict__ sbf, const float* __restrict__ W1a,
    const float* __restrict__ W1b, const int* __restrict__ rank,
    float* __restrict__ ta, float* __restrict__ tb)
{
    __shared__ float s_sbf[32 * SR];
    __shared__ float s_Wa[SR * BE];
    __shared__ float s_Wb[SR * BE];
    const int tid = threadIdx.x;
    const int t0  = blockIdx.x * 32;
    for (int i = tid; i < SR * BE; i += 256) { s_Wa[i] = W1a[i]; s_Wb[i] = W1b[i]; }
    {
        const float4* sb04 = reinterpret_cast<const float4*>(sbf + (size_t)t0 * SR);
        float4* s4 = reinterpret_cast<float4*>(s_sbf);
        for (int i = tid; i < 32 * SR / 4; i += 256) s4[i] = sb04[i];
    }
    __syncthreads();
    const int tt = tid >> 3, j = tid & 7;
    float sa = 0.0f, sb = 0.0f;
    #pragma unroll
    for (int i = 0; i < SR; ++i) {
        const float v = s_sbf[tt * SR + i];
        sa = fmaf(v, s_Wa[i * BE + j], sa);
        sb = fmaf(v, s_Wb[i * BE + j], sb);
    }
    const size_t p = (size_t)rank[t0 + tt] * BE + j;
    ta[p] = sa;
    tb[p] = sb;
}

// ---------------------------------------------------------------------------
// MFMA fused front (64-row tile, split-bf16, operand-swapped, 4m x 2n)
// ---------------------------------------------------------------------------
__global__ __launch_bounds__(256, 4) void k_front_mfma(
    const float* __restrict__ xe, const float* __restrict__ rbf,
    const short* __restrict__ wh, const short* __restrict__ wl,
    const float* __restrict__ bji, const float* __restrict__ bkj,
    const float* __restrict__ W1, const float* __restrict__ W2,
    float* __restrict__ xji, float* __restrict__ down)
{
    __shared__ short Ah[64 * 136];
    __shared__ short Al[64 * 136];
    __shared__ float s_tj[64 * 8];
    const int tid = threadIdx.x;
    const int r0  = blockIdx.x * 64;
    const int lane = tid & 63, wv = tid >> 6;
    const int lo4 = lane & 15, hi4 = lane >> 4;

    {
        const float4* XG = reinterpret_cast<const float4*>(xe);
        for (int i = tid; i < 64 * 32; i += 256) {
            const int row = i >> 5, c4 = i & 31;
            const float4 v = XG[(size_t)(r0 + row) * 32 + c4];
            unsigned h0, l0, h1, l1;
            pack2(v.x, v.y, h0, l0);
            pack2(v.z, v.w, h1, l1);
            *reinterpret_cast<uint2*>(&Ah[row * 136 + c4 * 4]) = make_uint2(h0, h1);
            *reinterpret_cast<uint2*>(&Al[row * 136 + c4 * 4]) = make_uint2(l0, l1);
        }
    }
    for (int i = tid; i < 64 * 8; i += 256) {
        const int row = i >> 3, j = i & 7;
        const float* rr_ = rbf + (size_t)(r0 + row) * R;
        float s = 0.0f;
        #pragma unroll
        for (int q = 0; q < R; ++q) s = fmaf(rr_[q], W1[q * BE + j], s);
        s_tj[i] = s;
    }
    __syncthreads();

    f32x4 acc[4][2], car[4][2];

    auto gemm = [&](const short* Wh, const short* Wl) {
        #pragma unroll
        for (int m = 0; m < 4; ++m)
            #pragma unroll
            for (int n = 0; n < 2; ++n) acc[m][n] = (f32x4)0.0f;
        for (int kt = 0; kt < 4; ++kt) {
            bf16x8 xh[4], xl[4], whf[2], wlf[2];
            #pragma unroll
            for (int m = 0; m < 4; ++m) {
                const int off = (m * 16 + lo4) * 136 + kt * 32 + hi4 * 8;
                xh[m] = *reinterpret_cast<const bf16x8*>(&Ah[off]);
                xl[m] = *reinterpret_cast<const bf16x8*>(&Al[off]);
            }
            #pragma unroll
            for (int n = 0; n < 2; ++n) {
                const size_t boff = ((size_t)((kt * 8 + wv * 2 + n) * 64) + lane) * 8;
                whf[n] = *reinterpret_cast<const bf16x8*>(&Wh[boff]);
                wlf[n] = *reinterpret_cast<const bf16x8*>(&Wl[boff]);
            }
            #pragma unroll
            for (int m = 0; m < 4; ++m)
                #pragma unroll
                for (int n = 0; n < 2; ++n) {
                    acc[m][n] = __builtin_amdgcn_mfma_f32_16x16x32_bf16(whf[n], xh[m], acc[m][n], 0, 0, 0);
                    acc[m][n] = __builtin_amdgcn_mfma_f32_16x16x32_bf16(wlf[n], xh[m], acc[m][n], 0, 0, 0);
                    acc[m][n] = __builtin_amdgcn_mfma_f32_16x16x32_bf16(whf[n], xl[m], acc[m][n], 0, 0, 0);
                }
        }
    };

    // p0: xji = silu(xe@Wji + bji)
    gemm(wh, wl);
    #pragma unroll
    for (int n = 0; n < 2; ++n) {
        const int feat0 = (wv * 2 + n) * 16 + hi4 * 4;
        const float4 bj = *reinterpret_cast<const float4*>(&bji[feat0]);
        #pragma unroll
        for (int m = 0; m < 4; ++m) {
            const int edge = r0 + m * 16 + lo4;
            float4 o = make_float4(silu_f(acc[m][n][0] + bj.x), silu_f(acc[m][n][1] + bj.y),
                                   silu_f(acc[m][n][2] + bj.z), silu_f(acc[m][n][3] + bj.w));
            *reinterpret_cast<float4*>(&xji[(size_t)edge * 128 + feat0]) = o;
        }
    }

    // p1: car = silu(xe@Wkj + bkj) .* rb
    gemm(wh + 16384, wl + 16384);
    #pragma unroll
    for (int n = 0; n < 2; ++n) {
        const int feat0 = (wv * 2 + n) * 16 + hi4 * 4;
        const float4 bk = *reinterpret_cast<const float4*>(&bkj[feat0]);
        float4 w2v[8];
        #pragma unroll
        for (int j = 0; j < 8; ++j)
            w2v[j] = *reinterpret_cast<const float4*>(&W2[j * 128 + feat0]);
        #pragma unroll
        for (int m = 0; m < 4; ++m) {
            const int erow = m * 16 + lo4;
            const float4 t0 = *reinterpret_cast<const float4*>(&s_tj[erow * 8]);
            const float4 t1 = *reinterpret_cast<const float4*>(&s_tj[erow * 8 + 4]);
            float rb0 = 0, rb1 = 0, rb2 = 0, rb3 = 0;
            const float tj[8] = {t0.x, t0.y, t0.z, t0.w, t1.x, t1.y, t1.z, t1.w};
            #pragma unroll
            for (int j = 0; j < 8; ++j) {
                rb0 = fmaf(tj[j], w2v[j].x, rb0); rb1 = fmaf(tj[j], w2v[j].y, rb1);
                rb2 = fmaf(tj[j], w2v[j].z, rb2); rb3 = fmaf(tj[j], w2v[j].w, rb3);
            }
            car[m][n][0] = silu_f(acc[m][n][0] + bk.x) * rb0;
            car[m][n][1] = silu_f(acc[m][n][1] + bk.y) * rb1;
            car[m][n][2] = silu_f(acc[m][n][2] + bk.z) * rb2;
            car[m][n][3] = silu_f(acc[m][n][3] + bk.w) * rb3;
        }
    }
    __syncthreads();
    #pragma unroll
    for (int m = 0; m < 4; ++m) {
        const int edge = m * 16 + lo4;
        #pragma unroll
        for (int n = 0; n < 2; ++n) {
            const int feat0 = (wv * 2 + n) * 16 + hi4 * 4;
            unsigned h0, l0, h1, l1;
            pack2(car[m][n][0], car[m][n][1], h0, l0);
            pack2(car[m][n][2], car[m][n][3], h1, l1);
            *reinterpret_cast<uint2*>(&Ah[edge * 136 + feat0]) = make_uint2(h0, h1);
            *reinterpret_cast<uint2*>(&Al[edge * 136 + feat0]) = make_uint2(l0, l1);
        }
    }
    __syncthreads();

    // p2: down = silu(A @ Wdown)  (N=64: wave wv owns feature tile wv)
    {
        const short* Wh = wh + 32768;
        const short* Wl = wl + 32768;
        f32x4 a2[4];
        #pragma unroll
        for (int m = 0; m < 4; ++m) a2[m] = (f32x4)0.0f;
        for (int kt = 0; kt < 4; ++kt) {
            bf16x8 xh[4], xl[4], whf, wlf;
            #pragma unroll
            for (int m = 0; m < 4; ++m) {
                const int off = (m * 16 + lo4) * 136 + kt * 32 + hi4 * 8;
                xh[m] = *reinterpret_cast<const bf16x8*>(&Ah[off]);
                xl[m] = *reinterpret_cast<const bf16x8*>(&Al[off]);
            }
            const size_t boff = ((size_t)((kt * 4 + wv) * 64) + lane) * 8;
            whf = *reinterpret_cast<const bf16x8*>(&Wh[boff]);
            wlf = *reinterpret_cast<const bf16x8*>(&Wl[boff]);
            #pragma unroll
            for (int m = 0; m < 4; ++m) {
                a2[m] = __builtin_amdgcn_mfma_f32_16x16x32_bf16(whf, xh[m], a2[m], 0, 0, 0);
                a2[m] = __builtin_amdgcn_mfma_f32_16x16x32_bf16(wlf, xh[m], a2[m], 0, 0, 0);
                a2[m] = __builtin_amdgcn_mfma_f32_16x16x32_bf16(whf, xl[m], a2[m], 0, 0, 0);
            }
        }
        const int feat0 = wv * 16 + hi4 * 4;
        #pragma unroll
        for (int m = 0; m < 4; ++m) {
            const int edge = r0 + m * 16 + lo4;
            *reinterpret_cast<float4*>(&down[(size_t)edge * 64 + feat0]) =
                make_float4(silu_f(a2[m][0]), silu_f(a2[m][1]),
                            silu_f(a2[m][2]), silu_f(a2[m][3]));
        }
    }
}

// ---------------------------------------------------------------------------
// Edge aggregation over sorted triplets (one wave per edge, 4-deep unroll)
// ---------------------------------------------------------------------------
__global__ __launch_bounds__(256) void k_agg(
    const int* __restrict__ rs, const int* __restrict__ kjs,
    const float* __restrict__ tmps, const float* __restrict__ down,
    const float* __restrict__ W2, float* __restrict__ agg)
{
    const int w = threadIdx.x >> 6, lane = threadIdx.x & 63;
    const int e = blockIdx.x * 4 + w;
    float w2[BE];
    #pragma unroll
    for (int j = 0; j < BE; ++j) w2[j] = W2[j * INTD + lane];

    const float4* tmps4 = reinterpret_cast<const float4*>(tmps);
    const int lo = rs[e], hi = rs[e + 1];
    float acc = 0.0f;
    int idx = lo;
    for (; idx + 3 < hi; idx += 4) {
        const int k0 = kjs[idx], k1 = kjs[idx + 1], k2 = kjs[idx + 2], k3 = kjs[idx + 3];
        const float4 a0 = tmps4[2*idx],   a1 = tmps4[2*idx+1];
        const float4 b0 = tmps4[2*idx+2], b1 = tmps4[2*idx+3];
        const float4 c0 = tmps4[2*idx+4], c1 = tmps4[2*idx+5];
        const float4 d0 = tmps4[2*idx+6], d1 = tmps4[2*idx+7];
        const float g0 = down[(size_t)k0 * INTD + lane];
        const float g1 = down[(size_t)k1 * INTD + lane];
        const float g2 = down[(size_t)k2 * INTD + lane];
        const float g3 = down[(size_t)k3 * INTD + lane];
        float s0 = a0.x*w2[0] + a0.y*w2[1] + a0.z*w2[2] + a0.w*w2[3]
                 + a1.x*w2[4] + a1.y*w2[5] + a1.z*w2[6] + a1.w*w2[7];
        float s1 = b0.x*w2[0] + b0.y*w2[1] + b0.z*w2[2] + b0.w*w2[3]
                 + b1.x*w2[4] + b1.y*w2[5] + b1.z*w2[6] + b1.w*w2[7];
        float s2 = c0.x*w2[0] + c0.y*w2[1] + c0.z*w2[2] + c0.w*w2[3]
                 + c1.x*w2[4] + c1.y*w2[5] + c1.z*w2[6] + c1.w*w2[7];
        float s3 = d0.x*w2[0] + d0.y*w2[1] + d0.z*w2[2] + d0.w*w2[3]
                 + d1.x*w2[4] + d1.y*w2[5] + d1.z*w2[6] + d1.w*w2[7];
        acc = fmaf(g0, s0, acc);
        acc = fmaf(g1, s1, acc);
        acc = fmaf(g2, s2, acc);
        acc = fmaf(g3, s3, acc);
    }
    for (; idx < hi; ++idx) {
        const int kj = kjs[idx];
        const float4 a0 = tmps4[2 * idx], a1 = tmps4[2 * idx + 1];
        const float d = down[(size_t)kj * INTD + lane];
        float sa = a0.x*w2[0] + a0.y*w2[1] + a0.z*w2[2] + a0.w*w2[3]
                 + a1.x*w2[4] + a1.y*w2[5] + a1.z*w2[6] + a1.w*w2[7];
        acc = fmaf(d, sa, acc);
    }
    agg[(size_t)e * INTD + lane] = acc;
}

// ---------------------------------------------------------------------------
// MFMA fused tail (64-row tile, split-bf16, operand-swapped, 4m x 2n)
// ---------------------------------------------------------------------------
__global__ __launch_bounds__(256, 4) void k_tail_mfma(
    const float* __restrict__ agg, const float* __restrict__ xji,
    const float* __restrict__ xe,
    const short* __restrict__ wh, const short* __restrict__ wl,
    const float* __restrict__ br, const float* __restrict__ blin,
    float* __restrict__ out)
{
    __shared__ short Ah[64 * 136];
    __shared__ short Al[64 * 136];
    const int tid = threadIdx.x;
    const int r0  = blockIdx.x * 64;
    const int lane = tid & 63, wv = tid >> 6;
    const int lo4 = lane & 15, hi4 = lane >> 4;

    {
        const float4* AG = reinterpret_cast<const float4*>(agg);
        for (int i = tid; i < 64 * 16; i += 256) {
            const int row = i >> 4, c4 = i & 15;
            const float4 v = AG[(size_t)(r0 + row) * 16 + c4];
            unsigned h0, l0, h1, l1;
            pack2(v.x, v.y, h0, l0);
            pack2(v.z, v.w, h1, l1);
            *reinterpret_cast<uint2*>(&Ah[row * 136 + c4 * 4]) = make_uint2(h0, h1);
            *reinterpret_cast<uint2*>(&Al[row * 136 + c4 * 4]) = make_uint2(l0, l1);
        }
    }
    __syncthreads();

    f32x4 acc[4][2], car[4][2];

    auto gemm = [&](const short* Wh, const short* Wl, int nkt) {
        #pragma unroll
        for (int m = 0; m < 4; ++m)
            #pragma unroll
            for (int n = 0; n < 2; ++n) acc[m][n] = (f32x4)0.0f;
        for (int kt = 0; kt < nkt; ++kt) {
            bf16x8 xh[4], xl[4], whf[2], wlf[2];
            #pragma unroll
            for (int m = 0; m < 4; ++m) {
                const int off = (m * 16 + lo4) * 136 + kt * 32 + hi4 * 8;
                xh[m] = *reinterpret_cast<const bf16x8*>(&Ah[off]);
                xl[m] = *reinterpret_cast<const bf16x8*>(&Al[off]);
            }
            #pragma unroll
            for (int n = 0; n < 2; ++n) {
                const size_t boff = ((size_t)((kt * 8 + wv * 2 + n) * 64) + lane) * 8;
                whf[n] = *reinterpret_cast<const bf16x8*>(&Wh[boff]);
                wlf[n] = *reinterpret_cast<const bf16x8*>(&Wl[boff]);
            }
            #pragma unroll
            for (int m = 0; m < 4; ++m)
                #pragma unroll
                for (int n = 0; n < 2; ++n) {
                    acc[m][n] = __builtin_amdgcn_mfma_f32_16x16x32_bf16(whf[n], xh[m], acc[m][n], 0, 0, 0);
                    acc[m][n] = __builtin_amdgcn_mfma_f32_16x16x32_bf16(wlf[n], xh[m], acc[m][n], 0, 0, 0);
                    acc[m][n] = __builtin_amdgcn_mfma_f32_16x16x32_bf16(whf[n], xl[m], acc[m][n], 0, 0, 0);
                }
        }
    };

    auto wrA = [&](f32x4 v[4][2]) {
        __syncthreads();
        #pragma unroll
        for (int m = 0; m < 4; ++m) {
            const int edge = m * 16 + lo4;
            #pragma unroll
            for (int n = 0; n < 2; ++n) {
                const int feat0 = (wv * 2 + n) * 16 + hi4 * 4;
                unsigned h0, l0, h1, l1;
                pack2(v[m][n][0], v[m][n][1], h0, l0);
                pack2(v[m][n][2], v[m][n][3], h1, l1);
                *reinterpret_cast<uint2*>(&Ah[edge * 136 + feat0]) = make_uint2(h0, h1);
                *reinterpret_cast<uint2*>(&Al[edge * 136 + feat0]) = make_uint2(l0, l1);
            }
        }
        __syncthreads();
    };

    // p0: car = silu(agg@Wup) + xji
    gemm(wh, wl, 2);
    #pragma unroll
    for (int n = 0; n < 2; ++n) {
        const int feat0 = (wv * 2 + n) * 16 + hi4 * 4;
        #pragma unroll
        for (int m = 0; m < 4; ++m) {
            const int edge = r0 + m * 16 + lo4;
            const float4 xv = *reinterpret_cast<const float4*>(&xji[(size_t)edge * 128 + feat0]);
            car[m][n][0] = silu_f(acc[m][n][0]) + xv.x;
            car[m][n][1] = silu_f(acc[m][n][1]) + xv.y;
            car[m][n][2] = silu_f(acc[m][n][2]) + xv.z;
            car[m][n][3] = silu_f(acc[m][n][3]) + xv.w;
        }
    }
    wrA(car);

    auto tphase = [&](const short* Wh, const short* Wl, const float* bias) {
        gemm(Wh, Wl, 4);
        #pragma unroll
        for (int n = 0; n < 2; ++n) {
            const int feat0 = (wv * 2 + n) * 16 + hi4 * 4;
            const float4 bv = *reinterpret_cast<const float4*>(&bias[feat0]);
            #pragma unroll
            for (int m = 0; m < 4; ++m) {
                acc[m][n][0] = silu_f(acc[m][n][0] + bv.x);
                acc[m][n][1] = silu_f(acc[m][n][1] + bv.y);
                acc[m][n][2] = silu_f(acc[m][n][2] + bv.z);
                acc[m][n][3] = silu_f(acc[m][n][3] + bv.w);
            }
        }
        wrA(acc);
    };
    auto cphase = [&](const short* Wh, const short* Wl, const float* bias) {
        gemm(Wh, Wl, 4);
        #pragma unroll
        for (int n = 0; n < 2; ++n) {
            const int feat0 = (wv * 2 + n) * 16 + hi4 * 4;
            const float4 bv = *reinterpret_cast<const float4*>(&bias[feat0]);
            #pragma unroll
            for (int m = 0; m < 4; ++m) {
                car[m][n][0] += silu_f(acc[m][n][0] + bv.x);
                car[m][n][1] += silu_f(acc[m][n][1] + bv.y);
                car[m][n][2] += silu_f(acc[m][n][2] + bv.z);
                car[m][n][3] += silu_f(acc[m][n][3] + bv.w);
            }
        }
        wrA(car);
    };

    tphase(wh + 8192,              wl + 8192,              br + 0 * 128);   // W0
    cphase(wh + 8192 + 16384,      wl + 8192 + 16384,      br + 1 * 128);   // W1

    // p3: car = silu(acc + blin) + xe
    gemm(wh + 8192 + 2 * 16384, wl + 8192 + 2 * 16384, 4);
    #pragma unroll
    for (int n = 0; n < 2; ++n) {
        const int feat0 = (wv * 2 + n) * 16 + hi4 * 4;
        const float4 bv = *reinterpret_cast<const float4*>(&blin[feat0]);
        #pragma unroll
        for (int m = 0; m < 4; ++m) {
            const int edge = r0 + m * 16 + lo4;
            const float4 xv = *reinterpret_cast<const float4*>(&xe[(size_t)edge * 128 + feat0]);
            car[m][n][0] = silu_f(acc[m][n][0] + bv.x) + xv.x;
            car[m][n][1] = silu_f(acc[m][n][1] + bv.y) + xv.y;
            car[m][n][2] = silu_f(acc[m][n][2] + bv.z) + xv.z;
            car[m][n][3] = silu_f(acc[m][n][3] + bv.w) + xv.w;
        }
    }
    wrA(car);

    tphase(wh + 8192 + 3 * 16384, wl + 8192 + 3 * 16384, br + 2 * 128);     // W2
    cphase(wh + 8192 + 4 * 16384, wl + 8192 + 4 * 16384, br + 3 * 128);     // W3
    tphase(wh + 8192 + 5 * 16384, wl + 8192 + 5 * 16384, br + 4 * 128);     // W4

    // p7: out = car + silu(acc + b5)
    gemm(wh + 8192 + 6 * 16384, wl + 8192 + 6 * 16384, 4);
    #pragma unroll
    for (int n = 0; n < 2; ++n) {
        const int feat0 = (wv * 2 + n) * 16 + hi4 * 4;
        const float4 bv = *reinterpret_cast<const float4*>(&br[5 * 128 + feat0]);
        #pragma unroll
        for (int m = 0; m < 4; ++m) {
            const int edge = r0 + m * 16 + lo4;
            float4 o = make_float4(car[m][n][0] + silu_f(acc[m][n][0] + bv.x),
                                   car[m][n][1] + silu_f(acc[m][n][1] + bv.y),
                                   car[m][n][2] + silu_f(acc[m][n][2] + bv.z),
                                   car[m][n][3] + silu_f(acc[m][n][3] + bv.w));
            *reinterpret_cast<float4*>(&out[(size_t)edge * 128 + feat0]) = o;
        }
    }
}

// ---------------------------------------------------------------------------
// Node aggregation (CSR over edge_i)
// ---------------------------------------------------------------------------
__global__ __launch_bounds__(256) void k_nodes(
    const int* __restrict__ rs, const int* __restrict__ perm,
    const float* __restrict__ rbf, const float* __restrict__ Wrbf,
    const float* __restrict__ xe, float* __restrict__ nodes)
{
    const int tid = threadIdx.x;
    const int n = blockIdx.x * 2 + (tid >> 7);
    const int c = tid & (H - 1);
    float wr[R];
    #pragma unroll
    for (int i = 0; i < R; ++i) wr[i] = Wrbf[i * H + c];
    float acc = 0.0f;
    const int lo = rs[n], hi = rs[n + 1];
    for (int idx = lo; idx < hi; ++idx) {
        const int e = perm[idx];
        const float* rb = rbf + (size_t)e * R;
        float g = 0.0f;
        #pragma unroll
        for (int i = 0; i < R; ++i) g = fmaf(rb[i], wr[i], g);
        acc = fmaf(g, xe[(size_t)e * H + c], acc);
    }
    nodes[(size_t)n * H + c] = acc;
}

// ---------------------------------------------------------------------------
// MFMA output chain (16-node tile, split-bf16, operand-swapped)
// ---------------------------------------------------------------------------
__global__ __launch_bounds__(256, 4) void k_outchain_mfma(
    const float* __restrict__ nodes, const short* __restrict__ wh,
    const short* __restrict__ wl, const float* __restrict__ bup,
    const float* __restrict__ blin, const float* __restrict__ Wout,
    float* __restrict__ P)
{
    __shared__ short Ah[16 * 264];
    __shared__ short Al[16 * 264];
    __shared__ float red[16 * 17];
    const int tid = threadIdx.x;
    const int n0  = blockIdx.x * 16;
    const int lane = tid & 63, wv = tid >> 6;
    const int lo4 = lane & 15, hi4 = lane >> 4;

    {
        const float4* NG = reinterpret_cast<const float4*>(nodes);
        for (int i = tid; i < 16 * 32; i += 256) {
            const int row = i >> 5, c4 = i & 31;
            const float4 v = NG[(size_t)(n0 + row) * 32 + c4];
            unsigned h0, l0, h1, l1;
            pack2(v.x, v.y, h0, l0);
            pack2(v.z, v.w, h1, l1);
            *reinterpret_cast<uint2*>(&Ah[row * 264 + c4 * 4]) = make_uint2(h0, h1);
            *reinterpret_cast<uint2*>(&Al[row * 264 + c4 * 4]) = make_uint2(l0, l1);
        }
    }
    __syncthreads();

    f32x4 acc[4];

    auto gemm = [&](const short* Wh, const short* Wl, int nkt) {
        #pragma unroll
        for (int n = 0; n < 4; ++n) acc[n] = (f32x4)0.0f;
        for (int kt = 0; kt < nkt; ++kt) {
            bf16x8 xh, xl, whf[4], wlf[4];
            {
                const int off = lo4 * 264 + kt * 32 + hi4 * 8;
                xh = *reinterpret_cast<const bf16x8*>(&Ah[off]);
                xl = *reinterpret_cast<const bf16x8*>(&Al[off]);
            }
            #pragma unroll
            for (int n = 0; n < 4; ++n) {
                const size_t boff = ((size_t)((kt * 16 + wv * 4 + n) * 64) + lane) * 8;
                whf[n] = *reinterpret_cast<const bf16x8*>(&Wh[boff]);
                wlf[n] = *reinterpret_cast<const bf16x8*>(&Wl[boff]);
            }
            #pragma unroll
            for (int n = 0; n < 4; ++n) {
                acc[n] = __builtin_amdgcn_mfma_f32_16x16x32_bf16(whf[n], xh, acc[n], 0, 0, 0);
                acc[n] = __builtin_amdgcn_mfma_f32_16x16x32_bf16(wlf[n], xh, acc[n], 0, 0, 0);
                acc[n] = __builtin_amdgcn_mfma_f32_16x16x32_bf16(whf[n], xl, acc[n], 0, 0, 0);
            }
        }
    };

    auto wrA = [&](bool dosilu, const float* bias) {
        __syncthreads();
        const int node = lo4;
        #pragma unroll
        for (int n = 0; n < 4; ++n) {
            const int feat0 = (wv * 4 + n) * 16 + hi4 * 4;
            const float4 bv = *reinterpret_cast<const float4*>(&bias[feat0]);
            float v0 = acc[n][0] + bv.x, v1 = acc[n][1] + bv.y;
            float v2 = acc[n][2] + bv.z, v3 = acc[n][3] + bv.w;
            if (dosilu) { v0 = silu_f(v0); v1 = silu_f(v1); v2 = silu_f(v2); v3 = silu_f(v3); }
            unsigned h0, l0, h1, l1;
            pack2(v0, v1, h0, l0);
            pack2(v2, v3, h1, l1);
            *reinterpret_cast<uint2*>(&Ah[node * 264 + feat0]) = make_uint2(h0, h1);
            *reinterpret_cast<uint2*>(&Al[node * 264 + feat0]) = make_uint2(l0, l1);
        }
        __syncthreads();
    };

    gemm(wh, wl, 4);                                   // nodes @ Wup (K=128)
    wrA(false, bup);
    gemm(wh + 32768, wl + 32768, 8);                   // @ Wl0 (K=256)
    wrA(true, blin + 0 * OE);
    gemm(wh + 32768 + 65536, wl + 32768 + 65536, 8);   // @ Wl1
    wrA(true, blin + 1 * OE);
    gemm(wh + 32768 + 2 * 65536, wl + 32768 + 2 * 65536, 8);  // @ Wl2

    // epilogue: t = silu(acc + b2); partial = t . Wout; reduce per node
    float part = 0.0f;
    #pragma unroll
    for (int n = 0; n < 4; ++n) {
        const int feat0 = (wv * 4 + n) * 16 + hi4 * 4;
        const float4 bv = *reinterpret_cast<const float4*>(&blin[2 * OE + feat0]);
        const float4 wo = *reinterpret_cast<const float4*>(&Wout[feat0]);
        part += silu_f(acc[n][0] + bv.x) * wo.x
              + silu_f(acc[n][1] + bv.y) * wo.y
              + silu_f(acc[n][2] + bv.z) * wo.z
              + silu_f(acc[n][3] + bv.w) * wo.w;
    }
    red[lo4 * 17 + wv * 4 + hi4] = part;
    __syncthreads();
    if (tid < 16) {
        float s = 0.0f;
        #pragma unroll
        for (int c = 0; c < 16; ++c) s += red[tid * 17 + c];
        P[n0 + tid] += s;
    }
}

// ---------------------------------------------------------------------------
extern "C" void kernel_launch(void* const* d_in, const int* in_sizes, int n_in,
                              void* d_out, int out_size, void* d_ws, size_t ws_size,
                              hipStream_t stream)
{
    (void)in_sizes; (void)n_in; (void)out_size; (void)ws_size;

    const float* x       = (const float*)d_in[0];
    const float* dist    = (const float*)d_in[1];
    const float* freq    = (const float*)d_in[2];
    const float* sbf     = (const float*)d_in[3];
    const int*   idx_kj  = (const int*)d_in[4];
    const int*   idx_ji  = (const int*)d_in[5];
    const int*   edge_i  = (const int*)d_in[6];
    const float* Wi_rbf1 = (const float*)d_in[8];
    const float* Wi_rbf2 = (const float*)d_in[9];
    const float* Wi_sbf1 = (const float*)d_in[10];
    const float* Wi_sbf2 = (const float*)d_in[11];
    const float* Wi_kj   = (const float*)d_in[12];
    const float* bi_kj   = (const float*)d_in[13];
    const float* Wi_ji   = (const float*)d_in[14];
    const float* bi_ji   = (const float*)d_in[15];
    const float* Wi_down = (const float*)d_in[16];
    const float* Wi_up   = (const float*)d_in[17];
    const float* Wi_res  = (const float*)d_in[18];
    const float* bi_res  = (const float*)d_in[19];
    const float* Wi_lin  = (const float*)d_in[20];
    const float* bi_lin  = (const float*)d_in[21];
    const float* Wo_rbf  = (const float*)d_in[22];
    const float* Wo_up   = (const float*)d_in[23];
    const float* bo_up   = (const float*)d_in[24];
    const float* Wo_lin  = (const float*)d_in[25];
    const float* bo_lin  = (const float*)d_in[26];
    const float* Wo_out  = (const float*)d_in[27];
    float* P = (float*)d_out;

    // ---- workspace carve-up ----
    float* w      = (float*)d_ws;
    float* rbf    = w;  w += (size_t)E * R;
    float* xeA    = w;  w += (size_t)E * H;
    float* xeB    = w;  w += (size_t)E * H;
    float* xji    = w;  w += (size_t)E * H;
    float* down   = w;  w += (size_t)E * INTD;
    float* agg    = w;  w += (size_t)E * INTD;
    float* tmp0   = w;  w += (size_t)T * BE;
    float* tmp1   = w;  w += (size_t)T * BE;
    float* nodes  = w;  w += (size_t)NN * H;
    int* ip       = (int*)w;
    int* trip_rs  = ip;  ip += E + 1;
    int* trip_cur = ip;  ip += E;
    int* rank_t   = ip;  ip += T;
    int* kjs      = ip;  ip += T;
    int* edge_rs  = ip;  ip += NN + 1;
    int* edge_cur = ip;  ip += NN;
    int* perm_e   = ip;  ip += E;
    int* bsumT    = ip;  ip += 64;
    int* bsumE    = ip;  ip += 64;
    short* wpk_hi = (short*)ip;
    short* wpk_lo = wpk_hi + 2 * PKB;
    short* wo_hi  = wpk_lo + 2 * PKB;
    short* wo_lo  = wo_hi + 3 * OPKB;

    // ---- CSR build ----
    hipMemsetAsync(trip_cur, 0, (size_t)E * sizeof(int), stream);
    hipMemsetAsync(edge_cur, 0, (size_t)NN * sizeof(int), stream);
    k_count<<<(T + 255) / 256, 256, 0, stream>>>(idx_ji, T, trip_cur);
    k_count<<<(E + 255) / 256, 256, 0, stream>>>(edge_i, E, edge_cur);
    const int nbT = (E + 2047) / 2048, nbE = (NN + 2047) / 2048;
    k_red<<<nbT, 256, 0, stream>>>(trip_cur, E, bsumT);
    k_scanb<<<1, 64, 0, stream>>>(bsumT, nbT);
    k_fill_rs<<<nbT, 256, 0, stream>>>(trip_cur, E, bsumT, trip_rs, trip_cur);
    k_red<<<nbE, 256, 0, stream>>>(edge_cur, NN, bsumE);
    k_scanb<<<1, 64, 0, stream>>>(bsumE, nbE);
    k_fill_rs<<<nbE, 256, 0, stream>>>(edge_cur, NN, bsumE, edge_rs, edge_cur);
    k_fill_trip<<<(T + 255) / 256, 256, 0, stream>>>(idx_ji, idx_kj, T, trip_cur, kjs, rank_t);
    k_fill<<<(E + 255) / 256, 256, 0, stream>>>(edge_i, E, edge_cur, perm_e);

    hipMemsetAsync(d_out, 0, (size_t)NN * sizeof(float), stream);
    k_rbf<<<(E + 255) / 256, 256, 0, stream>>>(dist, freq, rbf);
    k_pack<<<(2 * PKB + 255) / 256, 256, 0, stream>>>(Wi_ji, Wi_kj, Wi_down,
                                                      Wi_up, Wi_res, Wi_lin,
                                                      wpk_hi, wpk_lo);
    k_packo<<<(3 * OPKB + 255) / 256, 256, 0, stream>>>(Wo_up, Wo_lin, wo_hi, wo_lo);
    k_sbfproj2<<<T / 32, 256, 0, stream>>>(sbf, Wi_sbf1, Wi_sbf1 + (size_t)SR * BE,
                                           rank_t, tmp0, tmp1);

    auto out_block = [&](int b, const float* xe) {
        k_nodes<<<NN / 2, 256, 0, stream>>>(edge_rs, perm_e, rbf,
                                            Wo_rbf + (size_t)b * R * H, xe, nodes);
        k_outchain_mfma<<<NN / 16, 256, 0, stream>>>(nodes,
                                                     wo_hi + (size_t)b * OPKB,
                                                     wo_lo + (size_t)b * OPKB,
                                                     bo_up + (size_t)b * OE,
                                                     bo_lin + (size_t)b * 3 * OE,
                                                     Wo_out + (size_t)b * OE, P);
    };

    const int gE64 = E / 64;
    auto interact = [&](int b, const float* xe, const float* tmp, float* out) {
        k_front_mfma<<<gE64, 256, 0, stream>>>(xe, rbf,
                                               wpk_hi + (size_t)b * PKB,
                                               wpk_lo + (size_t)b * PKB,
                                               bi_ji + (size_t)b * H,
                                               bi_kj + (size_t)b * H,
                                               Wi_rbf1 + (size_t)b * R * BE,
                                               Wi_rbf2 + (size_t)b * BE * H,
                                               xji, down);
        k_agg<<<E / 4, 256, 0, stream>>>(trip_rs, kjs, tmp, down,
                                         Wi_sbf2 + (size_t)b * BE * INTD, agg);
        k_tail_mfma<<<gE64, 256, 0, stream>>>(agg, xji, xe,
                                              wpk_hi + (size_t)b * PKB + TAILO,
                                              wpk_lo + (size_t)b * PKB + TAILO,
                                              bi_res + (size_t)b * 3 * 2 * H,
                                              bi_lin + (size_t)b * H, out);
    };

    out_block(0, x);
    interact(0, x, tmp0, xeB);
    out_block(1, xeB);
    interact(1, xeB, tmp1, xeA);
    out_block(2, xeA);
}